// Round 2
// baseline (10769.565 us; speedup 1.0000x reference)
//
#include <hip/hip_runtime.h>

#define NB    16      // batches
#define NPTS  100000  // points per batch
#define NCH   16      // channels
#define KSEL  1024    // samples
#define SLOTS 16      // blocks per batch
#define TPB   256     // threads per block
#define CHUNK 6250    // NPTS / SLOTS
#define PPT   25      // ceil(CHUNK / TPB)

#define SCOPE __HIP_MEMORY_SCOPE_SYSTEM

// d_ws layout (bytes):
//   [0,     2048)   : barrier counters, cnt[b] at b*128 (u32)
//   [4096,  69632)  : candidates cand[parity][b][slot], 128B records
//   [69632, 135168) : idx list int[NB][KSEL]

__device__ __forceinline__ void combine(float ov, int oi, float& v, int& i) {
  if (ov > v || (ov == v && oi < i)) { v = ov; i = oi; }
}

__global__ __launch_bounds__(TPB, 1)
void fps_kernel(const float* __restrict__ points, const int* __restrict__ start_idx,
                unsigned int* __restrict__ ws_cnt, float* __restrict__ ws_cand,
                int* __restrict__ ws_idx) {
  // XCD-affinity swizzle: put all 16 blocks of a batch on (likely) one XCD.
  const int raw  = blockIdx.x;
  const int xcd  = raw & 7;
  const int s    = raw >> 3;
  const int b    = xcd + 8 * (s >> 4);
  const int slot = s & 15;

  const int tid  = threadIdx.x;
  const int lane = tid & 63;
  const int wid  = tid >> 6;

  const int base  = slot * CHUNK;      // start of this block's chunk (within batch)
  const float* __restrict__ pb = points + (size_t)b * NPTS * NCH;

  // ---- load xyz into registers, init min_d ----
  float px[PPT], py[PPT], pz[PPT], md[PPT];
  #pragma unroll
  for (int k = 0; k < PPT; ++k) {
    const int li = tid + (k << 8);     // local index within chunk
    const bool valid = li < CHUNK;
    float4 p = make_float4(0.f, 0.f, 0.f, 0.f);
    if (valid) p = *reinterpret_cast<const float4*>(pb + (size_t)(base + li) * NCH);
    px[k] = p.x; py[k] = p.y; pz[k] = p.z;
    md[k] = valid ? __builtin_inff() : -__builtin_inff();
  }

  __shared__ float s_rv[TPB / 64];
  __shared__ int   s_ri[TPB / 64];
  __shared__ float s_sx, s_sy, s_sz;

  // ---- initial selected point ----
  const int sidx = start_idx[b];
  float sx, sy, sz;
  {
    const float4 p = *reinterpret_cast<const float4*>(pb + (size_t)sidx * NCH);
    sx = p.x; sy = p.y; sz = p.z;
  }
  if (slot == 0 && tid == 0) ws_idx[b * KSEL] = sidx;

  unsigned int* cnt = ws_cnt + b * 32;  // 128B-padded counter per batch

  for (int i = 0; i < KSEL - 1; ++i) {
    // ---- phase A: distance update + thread-local argmax of updated min_d ----
    // Bit-exact vs numpy f32: explicit IEEE mul/add intrinsics, left-to-right
    // sum order ((dx*dx + dy*dy) + dz*dz), no FMA contraction possible.
    float bv = -__builtin_inff();
    int   bi = 0x7fffffff;
    #pragma unroll
    for (int k = 0; k < PPT; ++k) {
      const float dx = __fsub_rn(px[k], sx);
      const float dy = __fsub_rn(py[k], sy);
      const float dz = __fsub_rn(pz[k], sz);
      const float d  = __fadd_rn(__fadd_rn(__fmul_rn(dx, dx), __fmul_rn(dy, dy)),
                                 __fmul_rn(dz, dz));
      const float m  = fminf(md[k], d);
      md[k] = m;
      if (m > bv) { bv = m; bi = base + tid + (k << 8); }  // k asc -> first-max kept
    }

    // ---- wave reduce (val, idx) with first-index tie-break ----
    #pragma unroll
    for (int m = 32; m >= 1; m >>= 1) {
      const float ov = __shfl_xor(bv, m, 64);
      const int   oi = __shfl_xor(bi, m, 64);
      combine(ov, oi, bv, bi);
    }
    if (lane == 0) { s_rv[wid] = bv; s_ri[wid] = bi; }
    __syncthreads();
    bv = s_rv[0]; bi = s_ri[0];
    #pragma unroll
    for (int w = 1; w < TPB / 64; ++w) combine(s_rv[w], s_ri[w], bv, bi);
    // (bv, bi) now block-uniform

    // ---- owner thread publishes candidate record {val, idx, x, y, z} ----
    const int local = bi - base;
    if (tid == (local & 255)) {
      const int kk = local >> 8;
      float ox = 0.f, oy = 0.f, oz = 0.f;
      #pragma unroll
      for (int k = 0; k < PPT; ++k)     // static-index select (keep arrays in VGPRs)
        if (k == kk) { ox = px[k]; oy = py[k]; oz = pz[k]; }
      float* rec = ws_cand + (size_t)(((i & 1) * NB + b) * SLOTS + slot) * 32;
      __hip_atomic_store(rec + 0, bv, __ATOMIC_RELAXED, SCOPE);
      __hip_atomic_store(reinterpret_cast<int*>(rec) + 1, bi, __ATOMIC_RELAXED, SCOPE);
      __hip_atomic_store(rec + 2, ox, __ATOMIC_RELAXED, SCOPE);
      __hip_atomic_store(rec + 3, oy, __ATOMIC_RELAXED, SCOPE);
      __hip_atomic_store(rec + 4, oz, __ATOMIC_RELAXED, SCOPE);
      __hip_atomic_fetch_add(cnt, 1u, __ATOMIC_RELEASE, SCOPE);
    }

    // ---- per-batch barrier + global winner (wave 0 only) ----
    if (wid == 0) {
      const unsigned int target = (unsigned int)SLOTS * (unsigned int)(i + 1);
      while (__hip_atomic_load(cnt, __ATOMIC_ACQUIRE, SCOPE) < target)
        __builtin_amdgcn_s_sleep(1);

      float cv = -__builtin_inff(); int ci = 0x7fffffff;
      float cx = 0.f, cy = 0.f, cz = 0.f;
      const float* cb = ws_cand + (size_t)(((i & 1) * NB + b) * SLOTS) * 32;
      if (lane < SLOTS) {
        const float* rec = cb + lane * 32;
        cv = __hip_atomic_load(rec + 0, __ATOMIC_RELAXED, SCOPE);
        ci = __hip_atomic_load(reinterpret_cast<const int*>(rec) + 1, __ATOMIC_RELAXED, SCOPE);
        cx = __hip_atomic_load(rec + 2, __ATOMIC_RELAXED, SCOPE);
        cy = __hip_atomic_load(rec + 3, __ATOMIC_RELAXED, SCOPE);
        cz = __hip_atomic_load(rec + 4, __ATOMIC_RELAXED, SCOPE);
      }
      #pragma unroll
      for (int m = 8; m >= 1; m >>= 1) {    // reduce within 16 lanes (disjoint chunks -> idx tie-break ok)
        const float ov = __shfl_xor(cv, m, 64);
        const int   oi = __shfl_xor(ci, m, 64);
        const float ox = __shfl_xor(cx, m, 64);
        const float oy = __shfl_xor(cy, m, 64);
        const float oz = __shfl_xor(cz, m, 64);
        if (ov > cv || (ov == cv && oi < ci)) { cv = ov; ci = oi; cx = ox; cy = oy; cz = oz; }
      }
      if (lane == 0) {
        s_sx = cx; s_sy = cy; s_sz = cz;
        if (slot == 0) ws_idx[b * KSEL + i + 1] = ci;
      }
    }
    __syncthreads();
    sx = s_sx; sy = s_sy; sz = s_sz;
  }
}

__global__ void gather_kernel(const float* __restrict__ points,
                              const int* __restrict__ ws_idx,
                              float* __restrict__ out) {
  const int e = blockIdx.x * TPB + threadIdx.x;   // 0 .. NB*KSEL*NCH-1
  const int c = e & 15;
  const int k = (e >> 4) & (KSEL - 1);
  const int b = e >> 14;
  const int idx = ws_idx[b * KSEL + k];
  out[e] = points[((size_t)b * NPTS + idx) * NCH + c];
}

extern "C" void kernel_launch(void* const* d_in, const int* in_sizes, int n_in,
                              void* d_out, int out_size, void* d_ws, size_t ws_size,
                              hipStream_t stream) {
  const float* points    = (const float*)d_in[0];
  const int*   start_idx = (const int*)d_in[1];
  float*       out       = (float*)d_out;

  unsigned int* cnt  = (unsigned int*)d_ws;
  float*        cand = (float*)((char*)d_ws + 4096);
  int*          idxl = (int*)((char*)d_ws + 4096 + 65536);

  // barrier counters must start at 0 every launch (graph-replay safe)
  hipMemsetAsync(d_ws, 0, 2048, stream);

  fps_kernel<<<NB * SLOTS, TPB, 0, stream>>>(points, start_idx, cnt, cand, idxl);
  gather_kernel<<<(NB * KSEL * NCH) / TPB, TPB, 0, stream>>>(points, idxl, out);
}

// Round 3
// 4067.452 us; speedup vs baseline: 2.6477x; 2.6477x over previous
//
#include <hip/hip_runtime.h>

#define NB    16      // batches
#define NPTS  100000  // points per batch
#define NCH   16      // channels
#define KSEL  1024    // samples
#define SLOTS 16      // blocks per batch
#define TPB   256     // threads per block
#define CHUNK 6250    // NPTS / SLOTS
#define PPT   25      // CHUNK / TPB (ceil)

typedef unsigned long long u64;
#define SCOPE __HIP_MEMORY_SCOPE_AGENT

// d_ws layout (bytes):
//   [4096,  8192)   : cand u64[parity=2][NB][SLOTS]  (one 128B line per batch per parity)
//   [69632, 135168) : idx list int[NB][KSEL]
//
// Packed candidate word:
//   bits[63:32] = float bits of min_d value (>=0 -> bit order == float order)
//   bits[31:15] = 131071 - idx   (17 bits; larger == smaller idx -> first-index tie-break)
//   bits[14:5]  = tag = i+1      (1..1023, never 0 -> memset-0 never matches)
//   u64 max over slots == lexicographic (val desc, idx asc) winner.

__device__ __forceinline__ void combine(float ov, int oi, float& v, int& i) {
  if (ov > v || (ov == v && oi < i)) { v = ov; i = oi; }
}

__global__ __launch_bounds__(TPB, 1)
void fps_kernel(const float* __restrict__ points, const int* __restrict__ start_idx,
                u64* __restrict__ ws_cand, int* __restrict__ ws_idx) {
  // XCD-affinity swizzle: all 16 blocks of a batch on (likely) one XCD.
  const int raw  = blockIdx.x;
  const int xcd  = raw & 7;
  const int s    = raw >> 3;
  const int b    = xcd + 8 * (s >> 4);
  const int slot = s & 15;

  const int tid  = threadIdx.x;
  const int lane = tid & 63;
  const int wid  = tid >> 6;

  const int base = slot * CHUNK;
  const float* __restrict__ pb = points + (size_t)b * NPTS * NCH;

  // ---- load xyz into registers, init min_d ----
  float px[PPT], py[PPT], pz[PPT], md[PPT];
  #pragma unroll
  for (int k = 0; k < PPT; ++k) {
    const int li = tid + (k << 8);
    const bool valid = li < CHUNK;
    float4 p = make_float4(0.f, 0.f, 0.f, 0.f);
    if (valid) p = *reinterpret_cast<const float4*>(pb + (size_t)(base + li) * NCH);
    px[k] = p.x; py[k] = p.y; pz[k] = p.z;
    md[k] = valid ? __builtin_inff() : -__builtin_inff();
  }

  __shared__ float s_rv[2][4];   // parity-buffered block-reduce scratch
  __shared__ int   s_ri[2][4];

  // ---- initial selected point ----
  const int sidx = start_idx[b];
  float sx, sy, sz;
  {
    const float4 p = *reinterpret_cast<const float4*>(pb + (size_t)sidx * NCH);
    sx = p.x; sy = p.y; sz = p.z;
  }
  if (slot == 0 && tid == 0) ws_idx[b * KSEL] = sidx;

  u64* const myrec = ws_cand + (size_t)b * SLOTS + slot;
  const u64* const cb0 = ws_cand + (size_t)b * SLOTS;

  for (int i = 0; i < KSEL - 1; ++i) {
    const int par = i & 1;
    const size_t poff = (size_t)par * NB * SLOTS;

    // ---- distance update + thread-local argmax (bit-exact vs numpy f32) ----
    float bv = -__builtin_inff();
    int   bi = 0x7fffffff;
    #pragma unroll
    for (int k = 0; k < PPT; ++k) {
      const float dx = __fsub_rn(px[k], sx);
      const float dy = __fsub_rn(py[k], sy);
      const float dz = __fsub_rn(pz[k], sz);
      const float d  = __fadd_rn(__fadd_rn(__fmul_rn(dx, dx), __fmul_rn(dy, dy)),
                                 __fmul_rn(dz, dz));
      const float m  = fminf(md[k], d);
      md[k] = m;
      if (m > bv) { bv = m; bi = base + tid + (k << 8); }  // k asc -> first-max kept
    }

    // ---- wave reduce (val, idx), first-index tie-break ----
    #pragma unroll
    for (int m = 32; m >= 1; m >>= 1) {
      const float ov = __shfl_xor(bv, m, 64);
      const int   oi = __shfl_xor(bi, m, 64);
      combine(ov, oi, bv, bi);
    }
    if (lane == 0) { s_rv[par][wid] = bv; s_ri[par][wid] = bi; }
    __syncthreads();                       // the ONLY block barrier per iteration
    bv = s_rv[par][0]; bi = s_ri[par][0];
    #pragma unroll
    for (int w = 1; w < TPB / 64; ++w) combine(s_rv[par][w], s_ri[par][w], bv, bi);
    // (bv, bi) block-uniform

    // ---- publish: single relaxed 64-bit store ----
    const u64 key = ((u64)__float_as_uint(bv) << 32)
                  | ((u64)(unsigned)(131071 - bi) << 15)
                  | ((u64)(unsigned)(i + 1) << 5);
    if (tid == 0)
      __hip_atomic_store(myrec + poff, key, __ATOMIC_RELAXED, SCOPE);

    // ---- every wave polls all 16 slots (lane L owns slot L) ----
    const u64* cb = cb0 + poff;
    u64 w = 0;
    if (lane < SLOTS) {
      const unsigned want = (unsigned)(i + 1);
      do {
        w = __hip_atomic_load(cb + lane, __ATOMIC_RELAXED, SCOPE);
      } while ((unsigned)((w >> 5) & 0x3FF) != want);
    }
    // u64 max over 16 lanes (lanes >=16 hold 0)
    #pragma unroll
    for (int m = 8; m >= 1; m >>= 1) {
      const u64 o = __shfl_xor(w, m, 64);
      if (o > w) w = o;
    }
    w = __shfl(w, 0, 64);                  // broadcast wave-winner (lanes 0-15 group result)

    const int widx = 131071 - (int)((w >> 15) & 0x1FFFF);
    if (slot == 0 && tid == 0) ws_idx[b * KSEL + i + 1] = widx;

    // winner xyz from read-only points (L3-resident); uniform address per wave
    const float4 p = *reinterpret_cast<const float4*>(pb + (size_t)widx * NCH);
    sx = p.x; sy = p.y; sz = p.z;
  }
}

__global__ void gather_kernel(const float* __restrict__ points,
                              const int* __restrict__ ws_idx,
                              float* __restrict__ out) {
  const int e = blockIdx.x * TPB + threadIdx.x;   // 0 .. NB*KSEL*NCH-1
  const int c = e & 15;
  const int k = (e >> 4) & (KSEL - 1);
  const int b = e >> 14;
  const int idx = ws_idx[b * KSEL + k];
  out[e] = points[((size_t)b * NPTS + idx) * NCH + c];
}

extern "C" void kernel_launch(void* const* d_in, const int* in_sizes, int n_in,
                              void* d_out, int out_size, void* d_ws, size_t ws_size,
                              hipStream_t stream) {
  const float* points    = (const float*)d_in[0];
  const int*   start_idx = (const int*)d_in[1];
  float*       out       = (float*)d_out;

  u64* cand = (u64*)((char*)d_ws + 4096);
  int* idxl = (int*)((char*)d_ws + 4096 + 65536);

  // candidate tags must start at 0 every launch (graph-replay safe; tag 0 never expected)
  hipMemsetAsync(cand, 0, 2 * NB * SLOTS * sizeof(u64), stream);

  fps_kernel<<<NB * SLOTS, TPB, 0, stream>>>(points, start_idx, cand, idxl);
  gather_kernel<<<(NB * KSEL * NCH) / TPB, TPB, 0, stream>>>(points, idxl, out);
}